// Round 8
// baseline (786.213 us; speedup 1.0000x reference)
//
#include <hip/hip_runtime.h>
#include <hip/hip_bf16.h>

#define BATCH 32
#define NN 511
#define FEAT 512

typedef _Float16 half8 __attribute__((ext_vector_type(8)));
typedef float f32x4 __attribute__((ext_vector_type(4)));

__device__ __forceinline__ float bf2f(unsigned short u){
  union { unsigned int i; float f; } v; v.i = ((unsigned int)u) << 16; return v.f;
}
__device__ __forceinline__ float sigm(float x){ return 1.0f/(1.0f+expf(-x)); }
__device__ __forceinline__ float ldf(const void* p, long i, int f32){
  return f32 ? ((const float*)p)[i] : bf2f(((const unsigned short*)p)[i]);
}

// ---------------- dtype probe: 0 = bf16, 1 = fp32 ----------------
__global__ void detect_kernel(const unsigned short* __restrict__ p, int* __restrict__ flag){
  __shared__ int cnt;
  if (threadIdx.x == 0) cnt = 0;
  __syncthreads();
  int local = 0;
  for (int i = threadIdx.x; i < 4096; i += 256){
    unsigned short u = p[2*i];
    int e = (u >> 7) & 0xFF;
    if (u != 0 && e >= 117 && e <= 133) local++;
  }
  atomicAdd(&cnt, local);
  __syncthreads();
  if (threadIdx.x == 0) *flag = (cnt > 2048) ? 0 : 1;
}

// ---------------- adaptive conversions ----------------
__global__ void cvt16_kernel(const void* __restrict__ src, _Float16* __restrict__ dst,
                             int n, const int* __restrict__ flag){
  int i = blockIdx.x*blockDim.x + threadIdx.x;
  if (i >= n) return;
  dst[i] = (_Float16)ldf(src, i, *flag);
}
__global__ void cvt32_kernel(const void* __restrict__ src, float* __restrict__ dst,
                             int n, const int* __restrict__ flag){
  int i = blockIdx.x*blockDim.x + threadIdx.x;
  if (i >= n) return;
  dst[i] = ldf(src, i, *flag);
}

// ---------------- e_node/e_forw via MFMA: (32,1024) = eh(32,1024) @ [Wn;Wf]^T ----------
__global__ __launch_bounds__(64) void e_mfma(
    const _Float16* __restrict__ eh,
    const _Float16* __restrict__ Wn,
    const _Float16* __restrict__ Wf,
    float* __restrict__ e_node, float* __restrict__ e_forw)
{
  int lane = threadIdx.x;
  int m = lane & 15, quad = lane >> 4;
  int n = blockIdx.x*16 + m;
  const _Float16* wrow = (n < 512) ? (Wn + (long)n*1024) : (Wf + (long)(n-512)*1024);
  f32x4 acc[2] = {};
  for (int ks = 0; ks < 32; ks++){
    int kk = ks*32 + quad*8;
    half8 bfr = *(const half8*)(wrow + kk);
    #pragma unroll
    for (int i = 0; i < 2; i++){
      half8 afr = *(const half8*)(eh + (long)(i*16 + m)*1024 + kk);
      acc[i] = __builtin_amdgcn_mfma_f32_16x16x32_f16(afr, bfr, acc[i], 0, 0, 0);
    }
  }
  float* dst = (n < 512) ? e_node : e_forw;
  int col = (n < 512) ? n : (n - 512);
  #pragma unroll
  for (int i = 0; i < 2; i++)
    #pragma unroll
    for (int reg = 0; reg < 4; reg++){
      int b = i*16 + quad*4 + reg;
      dst[b*FEAT + col] = acc[i][reg];
    }
}

// ---------------- scores[b,i] = dot(feat16[b,i,:], e_node[b,:]) ----------------
__global__ void scores_kernel(const _Float16* __restrict__ feat,
                              const float* __restrict__ e_node,
                              float* __restrict__ scores){
  int b = blockIdx.y;
  int wave = threadIdx.x >> 6, lane = threadIdx.x & 63;
  int i = blockIdx.x*4 + wave;
  if (i >= NN) return;
  half8 v = *(const half8*)(feat + ((long)b*NN+i)*FEAT + lane*8);
  const float* en = e_node + b*FEAT + lane*8;
  float s = 0.f;
  #pragma unroll
  for (int q = 0; q < 8; q++) s += (float)v[q]*en[q];
  #pragma unroll
  for (int off = 32; off > 0; off >>= 1) s += __shfl_down(s, off, 64);
  if (lane == 0) scores[b*NN+i] = s;
}

// ---------------- feat2[b,i,:] = window-softmax-weighted sum of feat rows ----------------
__global__ void feat2_kernel(const _Float16* __restrict__ feat,
                             const int* __restrict__ finlist,
                             const float* __restrict__ scores,
                             _Float16* __restrict__ feat2){
  int i = blockIdx.x, b = blockIdx.y, t = threadIdx.x;
  int s0 = finlist[(b*NN+i)*2+0];
  int e0 = finlist[(b*NN+i)*2+1];
  s0 = min(max(s0, 0), NN-1);
  e0 = min(max(e0, s0), NN-1);
  int w = min(e0 - s0 + 1, 4);
  float sc[4]; float mx = -1e30f;
  #pragma unroll
  for (int q = 0; q < 4; q++){
    sc[q] = (q < w) ? scores[b*NN+s0+q] : -1e30f;
    mx = fmaxf(mx, sc[q]);
  }
  float p[4]; float den = 0.f;
  #pragma unroll
  for (int q = 0; q < 4; q++){ p[q] = (q < w) ? expf(sc[q]-mx) : 0.f; den += p[q]; }
  float inv = 1.f/den;
  #pragma unroll
  for (int q = 0; q < 4; q++) p[q] *= inv;
  #pragma unroll
  for (int e = 0; e < 4; e++){
    int f = t + e*128;
    float acc = 0.f;
    for (int q = 0; q < w; q++)
      acc += p[q]*(float)feat[((long)b*NN+s0+q)*FEAT + f];
    feat2[((long)b*NN+i)*FEAT+f] = (_Float16)acc;
  }
}

// ---------------- tiled MFMA GEMM, 128x128 tile, 4 waves, LDS double-buffer ----------------
// y<12: iou (M=32P, N=1536)  phase0: A=h[c0+2p]+h[c0+2p+1] W=Wiou (levels) | leaf single phase A=feat2[255+p] W=Wfeiou
//                             phase1: A=feat2[p0+p] W=Wfeiou
// y>=12: f (M=64P, N=512)     phase0: A=h[c0+q] W=Wf; phase1: A=feat2[p0+(q>>1)] W=Wfef
// LDS layout per buffer: [w(2)][sub(4)][slot(m*4+quad)(64)][8 fp16] = 4096 fp16; frag read = contiguous 1024B.
__global__ __launch_bounds__(256) void gemm_tile(
    int leaf, int P, int lp,
    const _Float16* __restrict__ feat2, const _Float16* __restrict__ hbuf,
    const _Float16* __restrict__ Wiou, const _Float16* __restrict__ Wfeiou,
    const _Float16* __restrict__ Wf,   const _Float16* __restrict__ Wfef,
    const float* __restrict__ biou, const float* __restrict__ bfv,
    _Float16* __restrict__ iou_out, _Float16* __restrict__ f_out)
{
  __shared__ __align__(16) _Float16 smem[16384];   // A: db*4096 ; B: 8192 + db*4096
  int tid = threadIdx.x;
  int lane = tid & 63, w = tid >> 6;
  int w0 = w & 1, w1 = w >> 1;
  int m = lane & 15, quad = lane >> 4;
  int y = blockIdx.y;
  bool isF = (!leaf) && (y >= 12);
  int Mtot, colbase;
  if (!isF){ Mtot = P << 5; colbase = y*128; }
  else     { Mtot = P << 6; colbase = (y-12)*128; }
  int rowbase = blockIdx.x*128;
  if (rowbase >= Mtot) return;

  // staging assignment: thread handles chunks tid and tid+256 for both A and B
  int a_r[2], a_c[2];
  int a_dst[2], b_dst[2];
  #pragma unroll
  for (int u = 0; u < 2; u++){
    int ch = tid + u*256;
    int r = ch >> 2, c = ch & 3;
    a_r[u] = r; a_c[u] = c;
    a_dst[u] = (r>>6)*2048 + ((r>>4)&3)*512 + ((r&15)*4 + c)*8;
    b_dst[u] = a_dst[u];          // same formula (col index plays role of row)
  }

  bool dual = false;
  const _Float16 *asrc[2], *asrc2[2], *bsrc[2];
  int p0 = P - 1, c0 = 2*P - 1;

  auto setup = [&](int phase){
    const _Float16* W = isF ? (phase ? Wfef : Wf)
                            : ((phase || leaf) ? Wfeiou : Wiou);
    dual = (!leaf && !isF && phase == 0);
    #pragma unroll
    for (int u = 0; u < 2; u++){
      bsrc[u] = W + (long)(colbase + a_r[u])*FEAT + a_c[u]*8;
      int r = rowbase + a_r[u];
      if (r > Mtot-1) r = Mtot-1;
      const _Float16* base; const _Float16* base2 = base2 = nullptr;
      if (leaf){
        int b = r >> lp, p = r & (P-1);
        base = feat2 + ((long)b*NN + 255 + p)*FEAT;
      } else if (!isF){
        int b = r >> lp, p = r & (P-1);
        if (phase == 0){ base = hbuf + ((long)b*NN + c0 + 2*p)*FEAT; base2 = base + FEAT; }
        else           { base = feat2 + ((long)b*NN + p0 + p)*FEAT; }
      } else {
        int b = r >> (lp+1), q = r & (2*P-1);
        if (phase == 0){ base = hbuf + ((long)b*NN + c0 + q)*FEAT; }
        else           { base = feat2 + ((long)b*NN + p0 + (q>>1))*FEAT; }
      }
      asrc[u] = base + a_c[u]*8;
      asrc2[u] = base2 ? (base2 + a_c[u]*8) : base;   // harmless if unused
    }
  };

  f32x4 acc[4][4] = {};
  half8 ra[2], ra2[2], rb[2];
  int aroff = ((lane & 15)*4 + (lane >> 4))*8;   // frag slot offset (fp16 units)

  setup(0);
  // prologue: stage K-step 0 into buffer 0
  #pragma unroll
  for (int u = 0; u < 2; u++){
    ra[u] = *(const half8*)(asrc[u]);
    if (dual) ra2[u] = *(const half8*)(asrc2[u]);
    rb[u] = *(const half8*)(bsrc[u]);
  }
  #pragma unroll
  for (int u = 0; u < 2; u++){
    half8 v = ra[u];
    if (dual) v = v + ra2[u];
    *(half8*)(smem + a_dst[u]) = v;
    *(half8*)(smem + 8192 + b_dst[u]) = rb[u];
  }

  int totK = leaf ? 16 : 32;
  for (int ks = 0; ks < totK; ks++){
    int db = ks & 1;
    bool have = (ks+1 < totK);
    bool dcur = dual;
    if (have){
      int kn = ks + 1;
      if (!leaf && kn == 16) setup(1);
      dcur = dual;
      int kin = kn & 15;
      #pragma unroll
      for (int u = 0; u < 2; u++){
        ra[u] = *(const half8*)(asrc[u] + (long)kin*32);
        if (dcur) ra2[u] = *(const half8*)(asrc2[u] + (long)kin*32);
        rb[u] = *(const half8*)(bsrc[u] + (long)kin*32);
      }
    }
    __syncthreads();
    const _Float16* A = smem + db*4096;
    const _Float16* B = smem + 8192 + db*4096;
    half8 afr[4], bfr[4];
    #pragma unroll
    for (int i = 0; i < 4; i++) afr[i] = *(const half8*)(A + (w0*4 + i)*512 + aroff);
    #pragma unroll
    for (int j = 0; j < 4; j++) bfr[j] = *(const half8*)(B + (w1*4 + j)*512 + aroff);
    #pragma unroll
    for (int i = 0; i < 4; i++)
      #pragma unroll
      for (int j = 0; j < 4; j++)
        acc[i][j] = __builtin_amdgcn_mfma_f32_16x16x32_f16(afr[i], bfr[j], acc[i][j], 0, 0, 0);
    if (have){
      _Float16* An = smem + (db^1)*4096;
      _Float16* Bn = smem + 8192 + (db^1)*4096;
      #pragma unroll
      for (int u = 0; u < 2; u++){
        half8 v = ra[u];
        if (dcur) v = v + ra2[u];
        *(half8*)(An + a_dst[u]) = v;
        *(half8*)(Bn + b_dst[u]) = rb[u];
      }
    }
  }

  const float* bias = isF ? bfv : biou;
  #pragma unroll
  for (int j = 0; j < 4; j++){
    int nl = w1*64 + j*16 + m;
    float bs = bias[colbase + nl];
    #pragma unroll
    for (int i = 0; i < 4; i++){
      #pragma unroll
      for (int reg = 0; reg < 4; reg++){
        int r = rowbase + w0*64 + i*16 + quad*4 + reg;
        if (r < Mtot){
          _Float16 val = (_Float16)(acc[i][j][reg] + bs);
          if (!isF) iou_out[(long)r*1536 + colbase + nl] = val;
          else      f_out[(long)r*512  + colbase + nl] = val;
        }
      }
    }
  }
}

// ---------------- level-0 pointwise (leaves) ----------------
__global__ void pw_leaf(const _Float16* __restrict__ iou, float* __restrict__ c,
                        _Float16* __restrict__ h){
  int r = blockIdx.x, b = blockIdx.y, t = threadIdx.x;
  const _Float16* row = iou + ((long)b*256 + r)*1536;
  long off = ((long)b*NN + 255 + r)*FEAT;
  #pragma unroll
  for (int e = 0; e < 2; e++){
    int f = t + e*256;
    float ig = (float)row[f], og = (float)row[FEAT+f], ug = (float)row[2*FEAT+f];
    float cn = sigm(ig)*fmaxf(ug, 0.f);
    float hn = sigm(og)*tanhf(cn);
    c[off+f] = cn;
    h[off+f] = (_Float16)hn;
  }
}

// ---------------- level-n pointwise ----------------
__global__ void pw_level(const _Float16* __restrict__ iou, const _Float16* __restrict__ fbuf,
                         float* __restrict__ c, _Float16* __restrict__ h,
                         int P, int p0, int c0){
  int r = blockIdx.x, b = blockIdx.y, t = threadIdx.x;
  const _Float16* row = iou + ((long)b*P + r)*1536;
  const _Float16* fl = fbuf + ((long)b*2*P + 2*r)*FEAT;
  const _Float16* fr = fl + FEAT;
  long cl = ((long)b*NN + c0 + 2*r)*FEAT;
  long cr = cl + FEAT;
  long po = ((long)b*NN + p0 + r)*FEAT;
  #pragma unroll
  for (int e = 0; e < 2; e++){
    int f = t + e*256;
    float csum = sigm((float)fl[f])*c[cl+f] + sigm((float)fr[f])*c[cr+f];
    float cn = sigm((float)row[f])*fmaxf((float)row[2*FEAT+f], 0.f) + csum;
    float hn = sigm((float)row[FEAT+f])*tanhf(cn);
    c[po+f] = cn;
    h[po+f] = (_Float16)hn;
  }
}

// ---------------- logits[b,i] = dot(h[b,i,:], e_forw[b,:]) ----------------
__global__ void logits_kernel(const _Float16* __restrict__ h,
                              const float* __restrict__ e_forw,
                              float* __restrict__ logits){
  int b = blockIdx.y;
  int wave = threadIdx.x >> 6, lane = threadIdx.x & 63;
  int i = blockIdx.x*4 + wave;
  if (i >= NN) return;
  half8 hv = *(const half8*)(h + ((long)b*NN+i)*FEAT + lane*8);
  const float* ef = e_forw + b*FEAT + lane*8;
  float s = 0.f;
  #pragma unroll
  for (int q = 0; q < 8; q++) s += (float)hv[q]*ef[q];
  #pragma unroll
  for (int off = 32; off > 0; off >>= 1) s += __shfl_down(s, off, 64);
  if (lane == 0) logits[b*NN+i] = s;
}

// ---------------- softmax over nodes + weighted sum -> fp32 out ----------------
// grid (32 batches, 4 col-groups of 128), 128 threads
__global__ void out_kernel(const _Float16* __restrict__ h,
                           const float* __restrict__ logits,
                           float* __restrict__ out){
  __shared__ float sprob[NN+1];
  __shared__ float red[128];
  int b = blockIdx.x, yc = blockIdx.y, t = threadIdx.x;
  float mx = -1e30f;
  for (int i = t; i < NN; i += 128) mx = fmaxf(mx, logits[b*NN+i]);
  red[t] = mx; __syncthreads();
  for (int s = 64; s > 0; s >>= 1){ if (t < s) red[t] = fmaxf(red[t], red[t+s]); __syncthreads(); }
  mx = red[0]; __syncthreads();
  float sum = 0.f;
  for (int i = t; i < NN; i += 128){ float p = expf(logits[b*NN+i]-mx); sprob[i] = p; sum += p; }
  red[t] = sum; __syncthreads();
  for (int s = 64; s > 0; s >>= 1){ if (t < s) red[t] += red[t+s]; __syncthreads(); }
  float inv = 1.f/red[0];
  __syncthreads();
  int f = yc*128 + t;
  float acc = 0.f;
  for (int i = 0; i < NN; i++) acc += sprob[i]*(float)h[((long)b*NN+i)*FEAT+f];
  out[b*FEAT+f] = acc*inv;   // OUTPUT IS FP32
}

extern "C" void kernel_launch(void* const* d_in, const int* in_sizes, int n_in,
                              void* d_out, int out_size, void* d_ws, size_t ws_size,
                              hipStream_t stream){
  (void)in_sizes; (void)n_in; (void)out_size; (void)ws_size;
  const void* feat_raw   = d_in[0];
  const int*  finlist    = (const int*)d_in[4];
  const void* eh_raw     = d_in[5];
  const void* Wln_raw    = d_in[6];
  const void* Wlf_raw    = d_in[7];
  const void* Wiou_raw   = d_in[8];
  const void* Wfeiou_raw = d_in[9];
  const void* bfeiou_raw = d_in[10];
  const void* Wf_raw     = d_in[11];
  const void* Wfef_raw   = d_in[12];
  const void* bfef_raw   = d_in[13];

  char* ws = (char*)d_ws;
  size_t off = 0;
  auto alloc = [&](size_t bytes)->char*{
    char* p = ws + off; off += (bytes + 255) & ~(size_t)255; return p;
  };
  int*      flag     = (int*)alloc(256);
  _Float16* feat_h   = (_Float16*)alloc((size_t)32*NN*FEAT*2);
  _Float16* Wiou_h   = (_Float16*)alloc((size_t)1536*512*2);
  _Float16* Wfeiou_h = (_Float16*)alloc((size_t)1536*512*2);
  _Float16* Wf_h     = (_Float16*)alloc((size_t)512*512*2);
  _Float16* Wfef_h   = (_Float16*)alloc((size_t)512*512*2);
  _Float16* eh_h     = (_Float16*)alloc((size_t)32*1024*2);
  _Float16* Wln_h    = (_Float16*)alloc((size_t)512*1024*2);
  _Float16* Wlf_h    = (_Float16*)alloc((size_t)512*1024*2);
  float*    bfeiou_f = (float*)alloc((size_t)1536*4);
  float*    bfef_f   = (float*)alloc((size_t)512*4);
  float*    e_node   = (float*)alloc((size_t)32*512*4);
  float*    e_forw   = (float*)alloc((size_t)32*512*4);
  float*    scores   = (float*)alloc((size_t)32*NN*4);
  _Float16* feat2    = (_Float16*)alloc((size_t)32*NN*FEAT*2);
  _Float16* h_half   = (_Float16*)alloc((size_t)32*NN*FEAT*2);
  float*    c_buf    = (float*)alloc((size_t)32*NN*FEAT*4);
  _Float16* iou_buf  = (_Float16*)alloc((size_t)32*256*1536*2);
  _Float16* f_buf    = (_Float16*)alloc((size_t)32*256*512*2);
  float*    logits   = (float*)alloc((size_t)32*NN*4);

  detect_kernel<<<dim3(1), 256, 0, stream>>>((const unsigned short*)feat_raw, flag);

  int nf = 32*NN*FEAT;
  cvt16_kernel<<<dim3((nf+255)/256), 256, 0, stream>>>(feat_raw, feat_h, nf, flag);
  cvt16_kernel<<<dim3((1536*512+255)/256), 256, 0, stream>>>(Wiou_raw, Wiou_h, 1536*512, flag);
  cvt16_kernel<<<dim3((1536*512+255)/256), 256, 0, stream>>>(Wfeiou_raw, Wfeiou_h, 1536*512, flag);
  cvt16_kernel<<<dim3((512*512+255)/256), 256, 0, stream>>>(Wf_raw, Wf_h, 512*512, flag);
  cvt16_kernel<<<dim3((512*512+255)/256), 256, 0, stream>>>(Wfef_raw, Wfef_h, 512*512, flag);
  cvt16_kernel<<<dim3((32*1024+255)/256), 256, 0, stream>>>(eh_raw, eh_h, 32*1024, flag);
  cvt16_kernel<<<dim3((512*1024+255)/256), 256, 0, stream>>>(Wln_raw, Wln_h, 512*1024, flag);
  cvt16_kernel<<<dim3((512*1024+255)/256), 256, 0, stream>>>(Wlf_raw, Wlf_h, 512*1024, flag);
  cvt32_kernel<<<dim3((1536+255)/256), 256, 0, stream>>>(bfeiou_raw, bfeiou_f, 1536, flag);
  cvt32_kernel<<<dim3((512+255)/256), 256, 0, stream>>>(bfef_raw, bfef_f, 512, flag);

  e_mfma<<<dim3(64), 64, 0, stream>>>(eh_h, Wln_h, Wlf_h, e_node, e_forw);
  scores_kernel<<<dim3(128,32), 256, 0, stream>>>(feat_h, e_node, scores);
  feat2_kernel<<<dim3(NN,32), 128, 0, stream>>>(feat_h, finlist, scores, feat2);

  // level 0: leaves: M = 8192 rows, 12 col-tiles of 128
  gemm_tile<<<dim3(64, 12), 256, 0, stream>>>(1, 256, 8,
      feat2, h_half, Wiou_h, Wfeiou_h, Wf_h, Wfef_h, bfeiou_f, bfef_f, iou_buf, f_buf);
  pw_leaf<<<dim3(256,32), 256, 0, stream>>>(iou_buf, c_buf, h_half);

  for (int n = 1; n <= 8; n++){
    int P = 1 << (8-n);
    int lp = 8 - n;
    int p0 = P - 1, c0 = 2*P - 1;
    int gx = P/2; if (gx < 1) gx = 1;
    gemm_tile<<<dim3(gx, 16), 256, 0, stream>>>(0, P, lp,
        feat2, h_half, Wiou_h, Wfeiou_h, Wf_h, Wfef_h, bfeiou_f, bfef_f, iou_buf, f_buf);
    pw_level<<<dim3(P,32), 256, 0, stream>>>(iou_buf, f_buf, c_buf, h_half, P, p0, c0);
  }

  logits_kernel<<<dim3(128,32), 256, 0, stream>>>(h_half, e_forw, logits);
  out_kernel<<<dim3(32,4), 128, 0, stream>>>(h_half, logits, (float*)d_out);
}

// Round 9
// 721.393 us; speedup vs baseline: 1.0899x; 1.0899x over previous
//
#include <hip/hip_runtime.h>
#include <hip/hip_bf16.h>

#define BATCH 32
#define NN 511
#define FEAT 512

typedef _Float16 half8 __attribute__((ext_vector_type(8)));
typedef float f32x4 __attribute__((ext_vector_type(4)));

__device__ __forceinline__ float bf2f(unsigned short u){
  union { unsigned int i; float f; } v; v.i = ((unsigned int)u) << 16; return v.f;
}
__device__ __forceinline__ float sigm(float x){ return 1.0f/(1.0f+expf(-x)); }
__device__ __forceinline__ float ldf(const void* p, long i, int f32){
  return f32 ? ((const float*)p)[i] : bf2f(((const unsigned short*)p)[i]);
}

// ---------------- dtype probe: 0 = bf16, 1 = fp32 ----------------
__global__ void detect_kernel(const unsigned short* __restrict__ p, int* __restrict__ flag){
  __shared__ int cnt;
  if (threadIdx.x == 0) cnt = 0;
  __syncthreads();
  int local = 0;
  for (int i = threadIdx.x; i < 4096; i += 256){
    unsigned short u = p[2*i];
    int e = (u >> 7) & 0xFF;
    if (u != 0 && e >= 117 && e <= 133) local++;
  }
  atomicAdd(&cnt, local);
  __syncthreads();
  if (threadIdx.x == 0) *flag = (cnt > 2048) ? 0 : 1;
}

// ---------------- adaptive conversions ----------------
__global__ void cvt16_kernel(const void* __restrict__ src, _Float16* __restrict__ dst,
                             int n, const int* __restrict__ flag){
  int i = blockIdx.x*blockDim.x + threadIdx.x;
  if (i >= n) return;
  dst[i] = (_Float16)ldf(src, i, *flag);
}
__global__ void cvt32_kernel(const void* __restrict__ src, float* __restrict__ dst,
                             int n, const int* __restrict__ flag){
  int i = blockIdx.x*blockDim.x + threadIdx.x;
  if (i >= n) return;
  dst[i] = ldf(src, i, *flag);
}

// ---------------- e_node/e_forw via MFMA: (32,1024) = eh(32,1024) @ [Wn;Wf]^T ----------
__global__ __launch_bounds__(64) void e_mfma(
    const _Float16* __restrict__ eh,
    const _Float16* __restrict__ Wn,
    const _Float16* __restrict__ Wf,
    float* __restrict__ e_node, float* __restrict__ e_forw)
{
  int lane = threadIdx.x;
  int m = lane & 15, quad = lane >> 4;
  int n = blockIdx.x*16 + m;
  const _Float16* wrow = (n < 512) ? (Wn + (long)n*1024) : (Wf + (long)(n-512)*1024);
  f32x4 acc[2] = {};
  for (int ks = 0; ks < 32; ks++){
    int kk = ks*32 + quad*8;
    half8 bfr = *(const half8*)(wrow + kk);
    #pragma unroll
    for (int i = 0; i < 2; i++){
      half8 afr = *(const half8*)(eh + (long)(i*16 + m)*1024 + kk);
      acc[i] = __builtin_amdgcn_mfma_f32_16x16x32_f16(afr, bfr, acc[i], 0, 0, 0);
    }
  }
  float* dst = (n < 512) ? e_node : e_forw;
  int col = (n < 512) ? n : (n - 512);
  #pragma unroll
  for (int i = 0; i < 2; i++)
    #pragma unroll
    for (int reg = 0; reg < 4; reg++){
      int b = i*16 + quad*4 + reg;
      dst[b*FEAT + col] = acc[i][reg];
    }
}

// ---------------- scores[b,i] = dot(feat16[b,i,:], e_node[b,:]) ----------------
__global__ void scores_kernel(const _Float16* __restrict__ feat,
                              const float* __restrict__ e_node,
                              float* __restrict__ scores){
  int b = blockIdx.y;
  int wave = threadIdx.x >> 6, lane = threadIdx.x & 63;
  int i = blockIdx.x*4 + wave;
  if (i >= NN) return;
  half8 v = *(const half8*)(feat + ((long)b*NN+i)*FEAT + lane*8);
  const float* en = e_node + b*FEAT + lane*8;
  float s = 0.f;
  #pragma unroll
  for (int q = 0; q < 8; q++) s += (float)v[q]*en[q];
  #pragma unroll
  for (int off = 32; off > 0; off >>= 1) s += __shfl_down(s, off, 64);
  if (lane == 0) scores[b*NN+i] = s;
}

// ---------------- feat2[b,i,:] = window-softmax-weighted sum of feat rows ----------------
__global__ void feat2_kernel(const _Float16* __restrict__ feat,
                             const int* __restrict__ finlist,
                             const float* __restrict__ scores,
                             _Float16* __restrict__ feat2){
  int i = blockIdx.x, b = blockIdx.y, t = threadIdx.x;
  int s0 = finlist[(b*NN+i)*2+0];
  int e0 = finlist[(b*NN+i)*2+1];
  s0 = min(max(s0, 0), NN-1);
  e0 = min(max(e0, s0), NN-1);
  int w = min(e0 - s0 + 1, 4);
  float sc[4]; float mx = -1e30f;
  #pragma unroll
  for (int q = 0; q < 4; q++){
    sc[q] = (q < w) ? scores[b*NN+s0+q] : -1e30f;
    mx = fmaxf(mx, sc[q]);
  }
  float p[4]; float den = 0.f;
  #pragma unroll
  for (int q = 0; q < 4; q++){ p[q] = (q < w) ? expf(sc[q]-mx) : 0.f; den += p[q]; }
  float inv = 1.f/den;
  #pragma unroll
  for (int q = 0; q < 4; q++) p[q] *= inv;
  #pragma unroll
  for (int e = 0; e < 4; e++){
    int f = t + e*128;
    float acc = 0.f;
    for (int q = 0; q < w; q++)
      acc += p[q]*(float)feat[((long)b*NN+s0+q)*FEAT + f];
    feat2[((long)b*NN+i)*FEAT+f] = (_Float16)acc;
  }
}

// ---------------- fused per-level MFMA GEMM (iou + f gates), global-row M ----------------
// 256 threads = 4 independent waves, each computing its own 64x64 tile
// (row tile = blockIdx.x*4 + wave). Per-wave code identical to R7's 1-wave version.
// M = 32*P rows; row r -> (b = r>>lp, p = r & (P-1)).
// col-group cg (blockIdx.y): cg<24 : iou cols  [cg*64 ..)      out iou_out[r*1536+n]
//                            24..31: f_left    [(cg-24)*64 ..) out f_out[(2r+0)*512+n]
//                            32..39: f_right   [(cg-32)*64 ..) out f_out[(2r+1)*512+n]
__global__ __launch_bounds__(256) void gemm_level(
    int leaf, int P, int lp,
    const _Float16* __restrict__ feat2, const _Float16* __restrict__ hbuf,
    const _Float16* __restrict__ Wiou, const _Float16* __restrict__ Wfeiou,
    const _Float16* __restrict__ Wf,   const _Float16* __restrict__ Wfef,
    const float* __restrict__ biou, const float* __restrict__ bf,
    _Float16* __restrict__ iou_out, _Float16* __restrict__ f_out)
{
  int tid = threadIdx.x;
  int lane = tid & 63, wv = tid >> 6;
  int m = lane & 15, quad = lane >> 4;
  int cg = blockIdx.y;
  int Mtot = P << 5;                 // 32*P
  int rowbase = (blockIdx.x*4 + wv)*64;
  if (rowbase >= Mtot) return;       // no barriers in kernel: early-exit safe
  int p0 = P - 1, c0 = 2*P - 1;

  int which, colbase;
  if (cg < 24)      { which = 0; colbase = cg*64; }
  else if (cg < 32) { which = 1; colbase = (cg-24)*64; }
  else              { which = 2; colbase = (cg-32)*64; }

  f32x4 acc[4][4] = {};

  int arow[4];
  #pragma unroll
  for (int i = 0; i < 4; i++){
    int r = rowbase + i*16 + m;
    arow[i] = (r < Mtot) ? r : (Mtot-1);
  }

  int nphase = leaf ? 1 : 2;
  for (int phase = 0; phase < nphase; ++phase){
    const _Float16* W;
    if (which == 0) W = (phase == 0 && !leaf) ? Wiou : Wfeiou;
    else            W = (phase == 0) ? Wf : Wfef;
    const _Float16* ap[4];
    bool dual = (!leaf && which == 0 && phase == 0);
    #pragma unroll
    for (int i = 0; i < 4; i++){
      int r = arow[i];
      int b = r >> lp, p = r & (P-1);
      int node; const _Float16* base;
      if (leaf)            { node = 255 + p; base = feat2; }
      else if (phase == 0) { node = c0 + 2*p + ((which == 2) ? 1 : 0); base = hbuf; }
      else                 { node = p0 + p; base = feat2; }
      ap[i] = base + ((long)b*NN + node)*FEAT;
    }
    for (int ks = 0; ks < 16; ++ks){
      int kk = ks*32 + quad*8;
      half8 afr[4], bfr[4];
      #pragma unroll
      for (int i = 0; i < 4; i++){
        half8 v = *(const half8*)(ap[i] + kk);
        if (dual){
          half8 v2 = *(const half8*)(ap[i] + FEAT + kk);
          v = v + v2;
        }
        afr[i] = v;
      }
      #pragma unroll
      for (int j = 0; j < 4; j++){
        int n = colbase + j*16 + m;
        bfr[j] = *(const half8*)(W + (long)n*FEAT + kk);
      }
      #pragma unroll
      for (int i = 0; i < 4; i++)
        #pragma unroll
        for (int j = 0; j < 4; j++)
          acc[i][j] = __builtin_amdgcn_mfma_f32_16x16x32_f16(afr[i], bfr[j], acc[i][j], 0, 0, 0);
    }
  }

  const float* bias = (which == 0) ? biou : bf;
  #pragma unroll
  for (int j = 0; j < 4; j++){
    int n = colbase + j*16 + m;
    float bs = bias[n];
    #pragma unroll
    for (int i = 0; i < 4; i++){
      #pragma unroll
      for (int reg = 0; reg < 4; reg++){
        int r = rowbase + i*16 + quad*4 + reg;
        if (r < Mtot){
          if (which == 0)
            iou_out[(long)r*1536 + n] = (_Float16)(acc[i][j][reg] + bs);
          else
            f_out[((long)2*r + (which-1))*512 + n] = (_Float16)(acc[i][j][reg] + bs);
        }
      }
    }
  }
}

// ---------------- level-0 pointwise (leaves) ----------------
__global__ void pw_leaf(const _Float16* __restrict__ iou, float* __restrict__ c,
                        _Float16* __restrict__ h){
  int r = blockIdx.x, b = blockIdx.y, t = threadIdx.x;
  const _Float16* row = iou + ((long)b*256 + r)*1536;
  long off = ((long)b*NN + 255 + r)*FEAT;
  #pragma unroll
  for (int e = 0; e < 2; e++){
    int f = t + e*256;
    float ig = (float)row[f], og = (float)row[FEAT+f], ug = (float)row[2*FEAT+f];
    float cn = sigm(ig)*fmaxf(ug, 0.f);
    float hn = sigm(og)*tanhf(cn);
    c[off+f] = cn;
    h[off+f] = (_Float16)hn;
  }
}

// ---------------- level-n pointwise ----------------
__global__ void pw_level(const _Float16* __restrict__ iou, const _Float16* __restrict__ fbuf,
                         float* __restrict__ c, _Float16* __restrict__ h,
                         int P, int p0, int c0){
  int r = blockIdx.x, b = blockIdx.y, t = threadIdx.x;
  const _Float16* row = iou + ((long)b*P + r)*1536;
  const _Float16* fl = fbuf + ((long)b*2*P + 2*r)*FEAT;
  const _Float16* fr = fl + FEAT;
  long cl = ((long)b*NN + c0 + 2*r)*FEAT;
  long cr = cl + FEAT;
  long po = ((long)b*NN + p0 + r)*FEAT;
  #pragma unroll
  for (int e = 0; e < 2; e++){
    int f = t + e*256;
    float csum = sigm((float)fl[f])*c[cl+f] + sigm((float)fr[f])*c[cr+f];
    float cn = sigm((float)row[f])*fmaxf((float)row[2*FEAT+f], 0.f) + csum;
    float hn = sigm((float)row[FEAT+f])*tanhf(cn);
    c[po+f] = cn;
    h[po+f] = (_Float16)hn;
  }
}

// ---------------- logits[b,i] = dot(h[b,i,:], e_forw[b,:]) ----------------
__global__ void logits_kernel(const _Float16* __restrict__ h,
                              const float* __restrict__ e_forw,
                              float* __restrict__ logits){
  int b = blockIdx.y;
  int wave = threadIdx.x >> 6, lane = threadIdx.x & 63;
  int i = blockIdx.x*4 + wave;
  if (i >= NN) return;
  half8 hv = *(const half8*)(h + ((long)b*NN+i)*FEAT + lane*8);
  const float* ef = e_forw + b*FEAT + lane*8;
  float s = 0.f;
  #pragma unroll
  for (int q = 0; q < 8; q++) s += (float)hv[q]*ef[q];
  #pragma unroll
  for (int off = 32; off > 0; off >>= 1) s += __shfl_down(s, off, 64);
  if (lane == 0) logits[b*NN+i] = s;
}

// ---------------- softmax over nodes + weighted sum -> fp32 out ----------------
// grid (32 batches, 4 col-groups of 128), 128 threads
__global__ void out_kernel(const _Float16* __restrict__ h,
                           const float* __restrict__ logits,
                           float* __restrict__ out){
  __shared__ float sprob[NN+1];
  __shared__ float red[128];
  int b = blockIdx.x, yc = blockIdx.y, t = threadIdx.x;
  float mx = -1e30f;
  for (int i = t; i < NN; i += 128) mx = fmaxf(mx, logits[b*NN+i]);
  red[t] = mx; __syncthreads();
  for (int s = 64; s > 0; s >>= 1){ if (t < s) red[t] = fmaxf(red[t], red[t+s]); __syncthreads(); }
  mx = red[0]; __syncthreads();
  float sum = 0.f;
  for (int i = t; i < NN; i += 128){ float p = expf(logits[b*NN+i]-mx); sprob[i] = p; sum += p; }
  red[t] = sum; __syncthreads();
  for (int s = 64; s > 0; s >>= 1){ if (t < s) red[t] += red[t+s]; __syncthreads(); }
  float inv = 1.f/red[0];
  __syncthreads();
  int f = yc*128 + t;
  float acc = 0.f;
  for (int i = 0; i < NN; i++) acc += sprob[i]*(float)h[((long)b*NN+i)*FEAT+f];
  out[b*FEAT+f] = acc*inv;   // OUTPUT IS FP32
}

extern "C" void kernel_launch(void* const* d_in, const int* in_sizes, int n_in,
                              void* d_out, int out_size, void* d_ws, size_t ws_size,
                              hipStream_t stream){
  (void)in_sizes; (void)n_in; (void)out_size; (void)ws_size;
  const void* feat_raw   = d_in[0];
  const int*  finlist    = (const int*)d_in[4];
  const void* eh_raw     = d_in[5];
  const void* Wln_raw    = d_in[6];
  const void* Wlf_raw    = d_in[7];
  const void* Wiou_raw   = d_in[8];
  const void* Wfeiou_raw = d_in[9];
  const void* bfeiou_raw = d_in[10];
  const void* Wf_raw     = d_in[11];
  const void* Wfef_raw   = d_in[12];
  const void* bfef_raw   = d_in[13];

  char* ws = (char*)d_ws;
  size_t off = 0;
  auto alloc = [&](size_t bytes)->char*{
    char* p = ws + off; off += (bytes + 255) & ~(size_t)255; return p;
  };
  int*      flag     = (int*)alloc(256);
  _Float16* feat_h   = (_Float16*)alloc((size_t)32*NN*FEAT*2);
  _Float16* Wiou_h   = (_Float16*)alloc((size_t)1536*512*2);
  _Float16* Wfeiou_h = (_Float16*)alloc((size_t)1536*512*2);
  _Float16* Wf_h     = (_Float16*)alloc((size_t)512*512*2);
  _Float16* Wfef_h   = (_Float16*)alloc((size_t)512*512*2);
  _Float16* eh_h     = (_Float16*)alloc((size_t)32*1024*2);
  _Float16* Wln_h    = (_Float16*)alloc((size_t)512*1024*2);
  _Float16* Wlf_h    = (_Float16*)alloc((size_t)512*1024*2);
  float*    bfeiou_f = (float*)alloc((size_t)1536*4);
  float*    bfef_f   = (float*)alloc((size_t)512*4);
  float*    e_node   = (float*)alloc((size_t)32*512*4);
  float*    e_forw   = (float*)alloc((size_t)32*512*4);
  float*    scores   = (float*)alloc((size_t)32*NN*4);
  _Float16* feat2    = (_Float16*)alloc((size_t)32*NN*FEAT*2);
  _Float16* h_half   = (_Float16*)alloc((size_t)32*NN*FEAT*2);
  float*    c_buf    = (float*)alloc((size_t)32*NN*FEAT*4);
  _Float16* iou_buf  = (_Float16*)alloc((size_t)32*256*1536*2);
  _Float16* f_buf    = (_Float16*)alloc((size_t)32*256*512*2);
  float*    logits   = (float*)alloc((size_t)32*NN*4);

  detect_kernel<<<dim3(1), 256, 0, stream>>>((const unsigned short*)feat_raw, flag);

  int nf = 32*NN*FEAT;
  cvt16_kernel<<<dim3((nf+255)/256), 256, 0, stream>>>(feat_raw, feat_h, nf, flag);
  cvt16_kernel<<<dim3((1536*512+255)/256), 256, 0, stream>>>(Wiou_raw, Wiou_h, 1536*512, flag);
  cvt16_kernel<<<dim3((1536*512+255)/256), 256, 0, stream>>>(Wfeiou_raw, Wfeiou_h, 1536*512, flag);
  cvt16_kernel<<<dim3((512*512+255)/256), 256, 0, stream>>>(Wf_raw, Wf_h, 512*512, flag);
  cvt16_kernel<<<dim3((512*512+255)/256), 256, 0, stream>>>(Wfef_raw, Wfef_h, 512*512, flag);
  cvt16_kernel<<<dim3((32*1024+255)/256), 256, 0, stream>>>(eh_raw, eh_h, 32*1024, flag);
  cvt16_kernel<<<dim3((512*1024+255)/256), 256, 0, stream>>>(Wln_raw, Wln_h, 512*1024, flag);
  cvt16_kernel<<<dim3((512*1024+255)/256), 256, 0, stream>>>(Wlf_raw, Wlf_h, 512*1024, flag);
  cvt32_kernel<<<dim3((1536+255)/256), 256, 0, stream>>>(bfeiou_raw, bfeiou_f, 1536, flag);
  cvt32_kernel<<<dim3((512+255)/256), 256, 0, stream>>>(bfef_raw, bfef_f, 512, flag);

  e_mfma<<<dim3(64), 64, 0, stream>>>(eh_h, Wln_h, Wlf_h, e_node, e_forw);
  scores_kernel<<<dim3(128,32), 256, 0, stream>>>(feat_h, e_node, scores);
  feat2_kernel<<<dim3(NN,32), 128, 0, stream>>>(feat_h, finlist, scores, feat2);

  // level 0: leaves: M = 8192 rows -> 32 row-blocks (4 waves x 64 rows), 24 col-groups
  gemm_level<<<dim3(32, 24), 256, 0, stream>>>(1, 256, 8,
      feat2, h_half, Wiou_h, Wfeiou_h, Wf_h, Wfef_h, bfeiou_f, bfef_f, iou_buf, f_buf);
  pw_leaf<<<dim3(256,32), 256, 0, stream>>>(iou_buf, c_buf, h_half);

  for (int n = 1; n <= 8; n++){
    int P = 1 << (8-n);
    int lp = 8 - n;
    int p0 = P - 1, c0 = 2*P - 1;
    int gx = (32*P + 255)/256;
    gemm_level<<<dim3(gx, 40), 256, 0, stream>>>(0, P, lp,
        feat2, h_half, Wiou_h, Wfeiou_h, Wf_h, Wfef_h, bfeiou_f, bfef_f, iou_buf, f_buf);
    pw_level<<<dim3(P,32), 256, 0, stream>>>(iou_buf, f_buf, c_buf, h_half, P, p0, c0);
  }

  logits_kernel<<<dim3(128,32), 256, 0, stream>>>(h_half, e_forw, logits);
  out_kernel<<<dim3(32,4), 128, 0, stream>>>(h_half, logits, (float*)d_out);
}

// Round 11
// 671.027 us; speedup vs baseline: 1.1717x; 1.0751x over previous
//
#include <hip/hip_runtime.h>
#include <hip/hip_bf16.h>

#define BATCH 32
#define NN 511
#define FEAT 512
#define NFEAT ((long)32*NN*FEAT)   // 8372224

typedef _Float16 half8 __attribute__((ext_vector_type(8)));
typedef float f32x4 __attribute__((ext_vector_type(4)));

__device__ __forceinline__ float bf2f(unsigned short u){
  union { unsigned int i; float f; } v; v.i = ((unsigned int)u) << 16; return v.f;
}
__device__ __forceinline__ float sigm(float x){ return 1.0f/(1.0f+expf(-x)); }
__device__ __forceinline__ float ldf(const void* p, long i, int f32){
  return f32 ? ((const float*)p)[i] : bf2f(((const unsigned short*)p)[i]);
}

// ---------------- dtype probe: 0 = bf16, 1 = fp32 ----------------
__global__ void detect_kernel(const unsigned short* __restrict__ p, int* __restrict__ flag){
  __shared__ int cnt;
  if (threadIdx.x == 0) cnt = 0;
  __syncthreads();
  int local = 0;
  for (int i = threadIdx.x; i < 4096; i += 256){
    unsigned short u = p[2*i];
    int e = (u >> 7) & 0xFF;
    if (u != 0 && e >= 117 && e <= 133) local++;
  }
  atomicAdd(&cnt, local);
  __syncthreads();
  if (threadIdx.x == 0) *flag = (cnt > 2048) ? 0 : 1;
}

// ---------------- single fused conversion kernel (all fp16 targets + 2 fp32 biases) -----
// segment table (8-elem aligned): feat | Wiou | Wfeiou | Wf | Wfef | eh | Wln | Wlf | biases
__global__ void cvt_all(
    const void* __restrict__ feat, const void* __restrict__ Wiou,
    const void* __restrict__ Wfeiou, const void* __restrict__ Wf,
    const void* __restrict__ Wfef, const void* __restrict__ eh,
    const void* __restrict__ Wln, const void* __restrict__ Wlf,
    const void* __restrict__ biou, const void* __restrict__ bfv,
    _Float16* __restrict__ feat_h, _Float16* __restrict__ Wiou_h,
    _Float16* __restrict__ Wfeiou_h, _Float16* __restrict__ Wf_h,
    _Float16* __restrict__ Wfef_h, _Float16* __restrict__ eh_h,
    _Float16* __restrict__ Wln_h, _Float16* __restrict__ Wlf_h,
    float* __restrict__ biou_f, float* __restrict__ bf_f,
    const int* __restrict__ flag)
{
  long g = ((long)blockIdx.x*256 + threadIdx.x)*8;
  int f32 = *flag;
  const long S1 = NFEAT;            // feat
  const long S2 = S1 + 786432;      // Wiou
  const long S3 = S2 + 786432;      // Wfeiou
  const long S4 = S3 + 262144;      // Wf
  const long S5 = S4 + 262144;      // Wfef
  const long S6 = S5 + 32768;       // eh
  const long S7 = S6 + 524288;      // Wln
  const long S8 = S7 + 524288;      // Wlf  (= 11550720)
  const long S9 = S8 + 1536;        // bias iou (fp32 out)
  const long SA = S9 + 512;         // bias f
  if (g >= SA) return;
  if (g >= S9){
    long o = g - S9;
    for (int q = 0; q < 8; q++) bf_f[o+q] = ldf(bfv, o+q, f32);
    return;
  }
  if (g >= S8){
    long o = g - S8;
    for (int q = 0; q < 8; q++) biou_f[o+q] = ldf(biou, o+q, f32);
    return;
  }
  const void* src; _Float16* dst; long off;
  if      (g < S1){ src=feat;   dst=feat_h;   off=g; }
  else if (g < S2){ src=Wiou;   dst=Wiou_h;   off=g-S1; }
  else if (g < S3){ src=Wfeiou; dst=Wfeiou_h; off=g-S2; }
  else if (g < S4){ src=Wf;     dst=Wf_h;     off=g-S3; }
  else if (g < S5){ src=Wfef;   dst=Wfef_h;   off=g-S4; }
  else if (g < S6){ src=eh;     dst=eh_h;     off=g-S5; }
  else if (g < S7){ src=Wln;    dst=Wln_h;    off=g-S6; }
  else            { src=Wlf;    dst=Wlf_h;    off=g-S7; }
  #pragma unroll
  for (int q = 0; q < 8; q++) dst[off+q] = (_Float16)ldf(src, off+q, f32);
}

// ---------------- e_node/e_forw via MFMA: (32,1024) = eh(32,1024) @ [Wn;Wf]^T ----------
__global__ __launch_bounds__(64) void e_mfma(
    const _Float16* __restrict__ eh,
    const _Float16* __restrict__ Wn,
    const _Float16* __restrict__ Wf,
    float* __restrict__ e_node, float* __restrict__ e_forw)
{
  int lane = threadIdx.x;
  int m = lane & 15, quad = lane >> 4;
  int n = blockIdx.x*16 + m;
  const _Float16* wrow = (n < 512) ? (Wn + (long)n*1024) : (Wf + (long)(n-512)*1024);
  f32x4 acc[2] = {};
  for (int ks = 0; ks < 32; ks++){
    int kk = ks*32 + quad*8;
    half8 bfr = *(const half8*)(wrow + kk);
    #pragma unroll
    for (int i = 0; i < 2; i++){
      half8 afr = *(const half8*)(eh + (long)(i*16 + m)*1024 + kk);
      acc[i] = __builtin_amdgcn_mfma_f32_16x16x32_f16(afr, bfr, acc[i], 0, 0, 0);
    }
  }
  float* dst = (n < 512) ? e_node : e_forw;
  int col = (n < 512) ? n : (n - 512);
  #pragma unroll
  for (int i = 0; i < 2; i++)
    #pragma unroll
    for (int reg = 0; reg < 4; reg++){
      int b = i*16 + quad*4 + reg;
      dst[b*FEAT + col] = acc[i][reg];
    }
}

// ---------------- feat2: per-node window softmax (computes own scores) -------------
// 256 threads: wave wv computes dot(feat[b,s0+wv], e_node[b]) for wv < w
__global__ void feat2_kernel(const _Float16* __restrict__ feat,
                             const int* __restrict__ finlist,
                             const float* __restrict__ e_node,
                             _Float16* __restrict__ feat2){
  __shared__ float sdots[4];
  int i = blockIdx.x, b = blockIdx.y, tid = threadIdx.x;
  int lane = tid & 63, wv = tid >> 6;
  int s0 = finlist[(b*NN+i)*2+0];
  int e0 = finlist[(b*NN+i)*2+1];
  s0 = min(max(s0, 0), NN-1);
  e0 = min(max(e0, s0), NN-1);
  int w = min(e0 - s0 + 1, 4);
  if (wv < w){
    half8 v = *(const half8*)(feat + ((long)b*NN + s0 + wv)*FEAT + lane*8);
    const float* en = e_node + b*FEAT + lane*8;
    float s = 0.f;
    #pragma unroll
    for (int q = 0; q < 8; q++) s += (float)v[q]*en[q];
    #pragma unroll
    for (int off = 32; off > 0; off >>= 1) s += __shfl_down(s, off, 64);
    if (lane == 0) sdots[wv] = s;
  }
  __syncthreads();
  float sc[4]; float mx = -1e30f;
  #pragma unroll
  for (int q = 0; q < 4; q++){
    sc[q] = (q < w) ? sdots[q] : -1e30f;
    mx = fmaxf(mx, sc[q]);
  }
  float p[4]; float den = 0.f;
  #pragma unroll
  for (int q = 0; q < 4; q++){ p[q] = (q < w) ? expf(sc[q]-mx) : 0.f; den += p[q]; }
  float inv = 1.f/den;
  #pragma unroll
  for (int q = 0; q < 4; q++) p[q] *= inv;
  #pragma unroll
  for (int e = 0; e < 2; e++){
    int f = tid + e*256;
    float acc = 0.f;
    for (int q = 0; q < w; q++)
      acc += p[q]*(float)feat[((long)b*NN+s0+q)*FEAT + f];
    feat2[((long)b*NN+i)*FEAT+f] = (_Float16)acc;
  }
}

// ---------------- fused per-level MFMA GEMM, software-pipelined K-loop ----------------
// One wave per 64x64 tile. M = 32*P rows; row r -> (b = r>>lp, p = r & (P-1)).
// cg<24 : iou cols [cg*64..)       out iou_out[r*1536+n]
// 24..31: f_left   [(cg-24)*64..)  out f_out[(2r+0)*512+n]
// 32..39: f_right  [(cg-32)*64..)  out f_out[(2r+1)*512+n]
__global__ __launch_bounds__(64) void gemm_level(
    int leaf, int P, int lp,
    const _Float16* __restrict__ feat2, const _Float16* __restrict__ hbuf,
    const _Float16* __restrict__ Wiou, const _Float16* __restrict__ Wfeiou,
    const _Float16* __restrict__ Wf,   const _Float16* __restrict__ Wfef,
    const float* __restrict__ biou, const float* __restrict__ bf,
    _Float16* __restrict__ iou_out, _Float16* __restrict__ f_out)
{
  int lane = threadIdx.x;
  int m = lane & 15, quad = lane >> 4;
  int cg = blockIdx.y;
  int Mtot = P << 5;
  int rowbase = blockIdx.x*64;
  if (rowbase >= Mtot) return;
  int p0 = P - 1, c0 = 2*P - 1;

  int which, colbase;
  if (cg < 24)      { which = 0; colbase = cg*64; }
  else if (cg < 32) { which = 1; colbase = (cg-24)*64; }
  else              { which = 2; colbase = (cg-32)*64; }

  f32x4 acc[4][4] = {};

  int arow[4];
  #pragma unroll
  for (int i = 0; i < 4; i++){
    int r = rowbase + i*16 + m;
    arow[i] = (r < Mtot) ? r : (Mtot-1);
  }

  int nphase = leaf ? 1 : 2;
  for (int phase = 0; phase < nphase; ++phase){
    const _Float16* W;
    if (which == 0) W = (phase == 0 && !leaf) ? Wiou : Wfeiou;
    else            W = (phase == 0) ? Wf : Wfef;
    const _Float16* ap[4];
    const _Float16* wp[4];
    bool dual = (!leaf && which == 0 && phase == 0);
    #pragma unroll
    for (int i = 0; i < 4; i++){
      int r = arow[i];
      int b = r >> lp, p = r & (P-1);
      int node; const _Float16* base;
      if (leaf)            { node = 255 + p; base = feat2; }
      else if (phase == 0) { node = c0 + 2*p + ((which == 2) ? 1 : 0); base = hbuf; }
      else                 { node = p0 + p; base = feat2; }
      ap[i] = base + ((long)b*NN + node)*FEAT + quad*8;
      wp[i] = W + (long)(colbase + i*16 + m)*FEAT + quad*8;
    }

    // software-pipelined K loop: prefetch k+1 into (na,nb) while MFMA-ing (ca,cb)
    half8 ca[4], cb[4];
    #pragma unroll
    for (int i = 0; i < 4; i++){
      half8 v = *(const half8*)(ap[i]);
      if (dual) v = v + *(const half8*)(ap[i] + FEAT);
      ca[i] = v;
      cb[i] = *(const half8*)(wp[i]);
    }
    #pragma unroll 1
    for (int ks = 0; ks < 16; ++ks){
      half8 na[4], nb[4];
      bool more = (ks < 15);
      if (more){
        long kk = (long)(ks+1)*32;
        #pragma unroll
        for (int i = 0; i < 4; i++){
          half8 v = *(const half8*)(ap[i] + kk);
          if (dual) v = v + *(const half8*)(ap[i] + FEAT + kk);
          na[i] = v;
          nb[i] = *(const half8*)(wp[i] + kk);
        }
      }
      #pragma unroll
      for (int i = 0; i < 4; i++)
        #pragma unroll
        for (int j = 0; j < 4; j++)
          acc[i][j] = __builtin_amdgcn_mfma_f32_16x16x32_f16(ca[i], cb[j], acc[i][j], 0, 0, 0);
      if (more){
        #pragma unroll
        for (int i = 0; i < 4; i++){ ca[i] = na[i]; cb[i] = nb[i]; }
      }
    }
  }

  const float* bias = (which == 0) ? biou : bf;
  #pragma unroll
  for (int j = 0; j < 4; j++){
    int n = colbase + j*16 + m;
    float bs = bias[n];
    #pragma unroll
    for (int i = 0; i < 4; i++){
      #pragma unroll
      for (int reg = 0; reg < 4; reg++){
        int r = rowbase + i*16 + quad*4 + reg;
        if (r < Mtot){
          if (which == 0)
            iou_out[(long)r*1536 + n] = (_Float16)(acc[i][j][reg] + bs);
          else
            f_out[((long)2*r + (which-1))*512 + n] = (_Float16)(acc[i][j][reg] + bs);
        }
      }
    }
  }
}

// ---------------- level-0 pointwise (leaves) ----------------
__global__ void pw_leaf(const _Float16* __restrict__ iou, float* __restrict__ c,
                        _Float16* __restrict__ h){
  int r = blockIdx.x, b = blockIdx.y, t = threadIdx.x;
  const _Float16* row = iou + ((long)b*256 + r)*1536;
  long off = ((long)b*NN + 255 + r)*FEAT;
  #pragma unroll
  for (int e = 0; e < 2; e++){
    int f = t + e*256;
    float ig = (float)row[f], og = (float)row[FEAT+f], ug = (float)row[2*FEAT+f];
    float cn = sigm(ig)*fmaxf(ug, 0.f);
    float hn = sigm(og)*tanhf(cn);
    c[off+f] = cn;
    h[off+f] = (_Float16)hn;
  }
}

// ---------------- level-n pointwise ----------------
__global__ void pw_level(const _Float16* __restrict__ iou, const _Float16* __restrict__ fbuf,
                         float* __restrict__ c, _Float16* __restrict__ h,
                         int P, int p0, int c0){
  int r = blockIdx.x, b = blockIdx.y, t = threadIdx.x;
  const _Float16* row = iou + ((long)b*P + r)*1536;
  const _Float16* fl = fbuf + ((long)b*2*P + 2*r)*FEAT;
  const _Float16* fr = fl + FEAT;
  long cl = ((long)b*NN + c0 + 2*r)*FEAT;
  long cr = cl + FEAT;
  long po = ((long)b*NN + p0 + r)*FEAT;
  #pragma unroll
  for (int e = 0; e < 2; e++){
    int f = t + e*256;
    float csum = sigm((float)fl[f])*c[cl+f] + sigm((float)fr[f])*c[cr+f];
    float cn = sigm((float)row[f])*fmaxf((float)row[2*FEAT+f], 0.f) + csum;
    float hn = sigm((float)row[FEAT+f])*tanhf(cn);
    c[po+f] = cn;
    h[po+f] = (_Float16)hn;
  }
}

// ---------------- logits[b,i] = dot(h[b,i,:], e_forw[b,:]) ----------------
__global__ void logits_kernel(const _Float16* __restrict__ h,
                              const float* __restrict__ e_forw,
                              float* __restrict__ logits){
  int b = blockIdx.y;
  int wave = threadIdx.x >> 6, lane = threadIdx.x & 63;
  int i = blockIdx.x*4 + wave;
  if (i >= NN) return;
  half8 hv = *(const half8*)(h + ((long)b*NN+i)*FEAT + lane*8);
  const float* ef = e_forw + b*FEAT + lane*8;
  float s = 0.f;
  #pragma unroll
  for (int q = 0; q < 8; q++) s += (float)hv[q]*ef[q];
  #pragma unroll
  for (int off = 32; off > 0; off >>= 1) s += __shfl_down(s, off, 64);
  if (lane == 0) logits[b*NN+i] = s;
}

// ---------------- softmax over nodes + weighted sum -> fp32 out ----------------
__global__ void out_kernel(const _Float16* __restrict__ h,
                           const float* __restrict__ logits,
                           float* __restrict__ out){
  __shared__ float sprob[NN+1];
  __shared__ float red[128];
  int b = blockIdx.x, yc = blockIdx.y, t = threadIdx.x;
  float mx = -1e30f;
  for (int i = t; i < NN; i += 128) mx = fmaxf(mx, logits[b*NN+i]);
  red[t] = mx; __syncthreads();
  for (int s = 64; s > 0; s >>= 1){ if (t < s) red[t] = fmaxf(red[t], red[t+s]); __syncthreads(); }
  mx = red[0]; __syncthreads();
  float sum = 0.f;
  for (int i = t; i < NN; i += 128){ float p = expf(logits[b*NN+i]-mx); sprob[i] = p; sum += p; }
  red[t] = sum; __syncthreads();
  for (int s = 64; s > 0; s >>= 1){ if (t < s) red[t] += red[t+s]; __syncthreads(); }
  float inv = 1.f/red[0];
  __syncthreads();
  int f = yc*128 + t;
  float acc = 0.f;
  for (int i = 0; i < NN; i++) acc += sprob[i]*(float)h[((long)b*NN+i)*FEAT+f];
  out[b*FEAT+f] = acc*inv;   // OUTPUT IS FP32
}

extern "C" void kernel_launch(void* const* d_in, const int* in_sizes, int n_in,
                              void* d_out, int out_size, void* d_ws, size_t ws_size,
                              hipStream_t stream){
  (void)in_sizes; (void)n_in; (void)out_size; (void)ws_size;
  const void* feat_raw   = d_in[0];
  const int*  finlist    = (const int*)d_in[4];
  const void* eh_raw     = d_in[5];
  const void* Wln_raw    = d_in[6];
  const void* Wlf_raw    = d_in[7];
  const void* Wiou_raw   = d_in[8];
  const void* Wfeiou_raw = d_in[9];
  const void* bfeiou_raw = d_in[10];
  const void* Wf_raw     = d_in[11];
  const void* Wfef_raw   = d_in[12];
  const void* bfef_raw   = d_in[13];

  char* ws = (char*)d_ws;
  size_t off = 0;
  auto alloc = [&](size_t bytes)->char*{
    char* p = ws + off; off += (bytes + 255) & ~(size_t)255; return p;
  };
  int*      flag     = (int*)alloc(256);
  _Float16* feat_h   = (_Float16*)alloc((size_t)NFEAT*2);
  _Float16* Wiou_h   = (_Float16*)alloc((size_t)1536*512*2);
  _Float16* Wfeiou_h = (_Float16*)alloc((size_t)1536*512*2);
  _Float16* Wf_h     = (_Float16*)alloc((size_t)512*512*2);
  _Float16* Wfef_h   = (_Float16*)alloc((size_t)512*512*2);
  _Float16* eh_h     = (_Float16*)alloc((size_t)32*1024*2);
  _Float16* Wln_h    = (_Float16*)alloc((size_t)512*1024*2);
  _Float16* Wlf_h    = (_Float16*)alloc((size_t)512*1024*2);
  float*    bfeiou_f = (float*)alloc((size_t)1536*4);
  float*    bfef_f   = (float*)alloc((size_t)512*4);
  float*    e_node   = (float*)alloc((size_t)32*512*4);
  float*    e_forw   = (float*)alloc((size_t)32*512*4);
  _Float16* feat2    = (_Float16*)alloc((size_t)NFEAT*2);
  _Float16* h_half   = (_Float16*)alloc((size_t)NFEAT*2);
  float*    c_buf    = (float*)alloc((size_t)NFEAT*4);
  _Float16* iou_buf  = (_Float16*)alloc((size_t)32*256*1536*2);
  _Float16* f_buf    = (_Float16*)alloc((size_t)32*256*512*2);
  float*    logits   = (float*)alloc((size_t)32*NN*4);

  detect_kernel<<<dim3(1), 256, 0, stream>>>((const unsigned short*)feat_raw, flag);

  // one fused conversion launch: ceil((11550720+2048)/8/256) blocks
  cvt_all<<<dim3(5641), 256, 0, stream>>>(
      feat_raw, Wiou_raw, Wfeiou_raw, Wf_raw, Wfef_raw, eh_raw, Wln_raw, Wlf_raw,
      bfeiou_raw, bfef_raw,
      feat_h, Wiou_h, Wfeiou_h, Wf_h, Wfef_h, eh_h, Wln_h, Wlf_h,
      bfeiou_f, bfef_f, flag);

  e_mfma<<<dim3(64), 64, 0, stream>>>(eh_h, Wln_h, Wlf_h, e_node, e_forw);
  feat2_kernel<<<dim3(NN,32), 256, 0, stream>>>(feat_h, finlist, e_node, feat2);

  // level 0: leaves: M = 8192 rows, 24 iou col-groups
  gemm_level<<<dim3(128, 24), 64, 0, stream>>>(1, 256, 8,
      feat2, h_half, Wiou_h, Wfeiou_h, Wf_h, Wfef_h,
      bfeiou_f, bfef_f, iou_buf, f_buf);
  pw_leaf<<<dim3(256,32), 256, 0, stream>>>(iou_buf, c_buf, h_half);

  for (int n = 1; n <= 8; n++){
    int P = 1 << (8-n);
    int lp = 8 - n;
    int p0 = P - 1, c0 = 2*P - 1;
    int gx = (32*P + 63)/64;
    gemm_level<<<dim3(gx, 40), 64, 0, stream>>>(0, P, lp,
        feat2, h_half, Wiou_h, Wfeiou_h, Wf_h, Wfef_h, bfeiou_f, bfef_f, iou_buf, f_buf);
    pw_level<<<dim3(P,32), 256, 0, stream>>>(iou_buf, f_buf, c_buf, h_half, P, p0, c0);
  }

  logits_kernel<<<dim3(128,32), 256, 0, stream>>>(h_half, e_forw, logits);
  out_kernel<<<dim3(32,4), 128, 0, stream>>>(h_half, logits, (float*)d_out);
}

// Round 12
// 651.196 us; speedup vs baseline: 1.2073x; 1.0305x over previous
//
#include <hip/hip_runtime.h>
#include <hip/hip_bf16.h>

#define BATCH 32
#define NN 511
#define FEAT 512
#define NFEAT ((long)32*NN*FEAT)   // 8372224

typedef _Float16 half8 __attribute__((ext_vector_type(8)));
typedef float f32x4 __attribute__((ext_vector_type(4)));

__device__ __forceinline__ float bf2f(unsigned short u){
  union { unsigned int i; float f; } v; v.i = ((unsigned int)u) << 16; return v.f;
}
__device__ __forceinline__ float sigm(float x){ return 1.0f/(1.0f+expf(-x)); }
__device__ __forceinline__ float ldf(const void* p, long i, int f32){
  return f32 ? ((const float*)p)[i] : bf2f(((const unsigned short*)p)[i]);
}

// ---------------- dtype probe: 0 = bf16, 1 = fp32 ----------------
__global__ void detect_kernel(const unsigned short* __restrict__ p, int* __restrict__ flag){
  __shared__ int cnt;
  if (threadIdx.x == 0) cnt = 0;
  __syncthreads();
  int local = 0;
  for (int i = threadIdx.x; i < 4096; i += 256){
    unsigned short u = p[2*i];
    int e = (u >> 7) & 0xFF;
    if (u != 0 && e >= 117 && e <= 133) local++;
  }
  atomicAdd(&cnt, local);
  __syncthreads();
  if (threadIdx.x == 0) *flag = (cnt > 2048) ? 0 : 1;
}

// ---------------- single fused conversion kernel (all fp16 targets + 2 fp32 biases) -----
__global__ void cvt_all(
    const void* __restrict__ feat, const void* __restrict__ Wiou,
    const void* __restrict__ Wfeiou, const void* __restrict__ Wf,
    const void* __restrict__ Wfef, const void* __restrict__ eh,
    const void* __restrict__ Wln, const void* __restrict__ Wlf,
    const void* __restrict__ biou, const void* __restrict__ bfv,
    _Float16* __restrict__ feat_h, _Float16* __restrict__ Wiou_h,
    _Float16* __restrict__ Wfeiou_h, _Float16* __restrict__ Wf_h,
    _Float16* __restrict__ Wfef_h, _Float16* __restrict__ eh_h,
    _Float16* __restrict__ Wln_h, _Float16* __restrict__ Wlf_h,
    float* __restrict__ biou_f, float* __restrict__ bf_f,
    const int* __restrict__ flag)
{
  long g = ((long)blockIdx.x*256 + threadIdx.x)*8;
  int f32 = *flag;
  const long S1 = NFEAT;            // feat
  const long S2 = S1 + 786432;      // Wiou
  const long S3 = S2 + 786432;      // Wfeiou
  const long S4 = S3 + 262144;      // Wf
  const long S5 = S4 + 262144;      // Wfef
  const long S6 = S5 + 32768;       // eh
  const long S7 = S6 + 524288;      // Wln
  const long S8 = S7 + 524288;      // Wlf  (= 11550720)
  const long S9 = S8 + 1536;        // bias iou (fp32 out)
  const long SA = S9 + 512;         // bias f
  if (g >= SA) return;
  if (g >= S9){
    long o = g - S9;
    for (int q = 0; q < 8; q++) bf_f[o+q] = ldf(bfv, o+q, f32);
    return;
  }
  if (g >= S8){
    long o = g - S8;
    for (int q = 0; q < 8; q++) biou_f[o+q] = ldf(biou, o+q, f32);
    return;
  }
  const void* src; _Float16* dst; long off;
  if      (g < S1){ src=feat;   dst=feat_h;   off=g; }
  else if (g < S2){ src=Wiou;   dst=Wiou_h;   off=g-S1; }
  else if (g < S3){ src=Wfeiou; dst=Wfeiou_h; off=g-S2; }
  else if (g < S4){ src=Wf;     dst=Wf_h;     off=g-S3; }
  else if (g < S5){ src=Wfef;   dst=Wfef_h;   off=g-S4; }
  else if (g < S6){ src=eh;     dst=eh_h;     off=g-S5; }
  else if (g < S7){ src=Wln;    dst=Wln_h;    off=g-S6; }
  else            { src=Wlf;    dst=Wlf_h;    off=g-S7; }
  #pragma unroll
  for (int q = 0; q < 8; q++) dst[off+q] = (_Float16)ldf(src, off+q, f32);
}

// ---------------- e_node/e_forw via MFMA: (32,1024) = eh(32,1024) @ [Wn;Wf]^T ----------
__global__ __launch_bounds__(64) void e_mfma(
    const _Float16* __restrict__ eh,
    const _Float16* __restrict__ Wn,
    const _Float16* __restrict__ Wf,
    float* __restrict__ e_node, float* __restrict__ e_forw)
{
  int lane = threadIdx.x;
  int m = lane & 15, quad = lane >> 4;
  int n = blockIdx.x*16 + m;
  const _Float16* wrow = (n < 512) ? (Wn + (long)n*1024) : (Wf + (long)(n-512)*1024);
  f32x4 acc[2] = {};
  for (int ks = 0; ks < 32; ks++){
    int kk = ks*32 + quad*8;
    half8 bfr = *(const half8*)(wrow + kk);
    #pragma unroll
    for (int i = 0; i < 2; i++){
      half8 afr = *(const half8*)(eh + (long)(i*16 + m)*1024 + kk);
      acc[i] = __builtin_amdgcn_mfma_f32_16x16x32_f16(afr, bfr, acc[i], 0, 0, 0);
    }
  }
  float* dst = (n < 512) ? e_node : e_forw;
  int col = (n < 512) ? n : (n - 512);
  #pragma unroll
  for (int i = 0; i < 2; i++)
    #pragma unroll
    for (int reg = 0; reg < 4; reg++){
      int b = i*16 + quad*4 + reg;
      dst[b*FEAT + col] = acc[i][reg];
    }
}

// ---------------- feat2: per-node window softmax (computes own scores) -------------
__global__ void feat2_kernel(const _Float16* __restrict__ feat,
                             const int* __restrict__ finlist,
                             const float* __restrict__ e_node,
                             _Float16* __restrict__ feat2){
  __shared__ float sdots[4];
  int i = blockIdx.x, b = blockIdx.y, tid = threadIdx.x;
  int lane = tid & 63, wv = tid >> 6;
  int s0 = finlist[(b*NN+i)*2+0];
  int e0 = finlist[(b*NN+i)*2+1];
  s0 = min(max(s0, 0), NN-1);
  e0 = min(max(e0, s0), NN-1);
  int w = min(e0 - s0 + 1, 4);
  if (wv < w){
    half8 v = *(const half8*)(feat + ((long)b*NN + s0 + wv)*FEAT + lane*8);
    const float* en = e_node + b*FEAT + lane*8;
    float s = 0.f;
    #pragma unroll
    for (int q = 0; q < 8; q++) s += (float)v[q]*en[q];
    #pragma unroll
    for (int off = 32; off > 0; off >>= 1) s += __shfl_down(s, off, 64);
    if (lane == 0) sdots[wv] = s;
  }
  __syncthreads();
  float sc[4]; float mx = -1e30f;
  #pragma unroll
  for (int q = 0; q < 4; q++){
    sc[q] = (q < w) ? sdots[q] : -1e30f;
    mx = fmaxf(mx, sc[q]);
  }
  float p[4]; float den = 0.f;
  #pragma unroll
  for (int q = 0; q < 4; q++){ p[q] = (q < w) ? expf(sc[q]-mx) : 0.f; den += p[q]; }
  float inv = 1.f/den;
  #pragma unroll
  for (int q = 0; q < 4; q++) p[q] *= inv;
  #pragma unroll
  for (int e = 0; e < 2; e++){
    int f = tid + e*256;
    float acc = 0.f;
    for (int q = 0; q < w; q++)
      acc += p[q]*(float)feat[((long)b*NN+s0+q)*FEAT + f];
    feat2[((long)b*NN+i)*FEAT+f] = (_Float16)acc;
  }
}

// ---------------- fused per-level MFMA GEMM, depth-2 pipelined, L2-friendly grid ------
// GRID: bx = col-group (fast-varying -> blocks sharing A rows run together; full 4 MB
//       weight set stays L2-resident), by = row-tile.
// One wave per 64x64 tile. M = 32*P rows; row r -> (b = r>>lp, p = r & (P-1)).
// cg<24 : iou cols [cg*64..)       out iou_out[r*1536+n]
// 24..31: f_left   [(cg-24)*64..)  out f_out[(2r+0)*512+n]
// 32..39: f_right  [(cg-32)*64..)  out f_out[(2r+1)*512+n]
__global__ __launch_bounds__(64) void gemm_level(
    int leaf, int P, int lp,
    const _Float16* __restrict__ feat2, const _Float16* __restrict__ hbuf,
    const _Float16* __restrict__ Wiou, const _Float16* __restrict__ Wfeiou,
    const _Float16* __restrict__ Wf,   const _Float16* __restrict__ Wfef,
    const float* __restrict__ biou, const float* __restrict__ bf,
    _Float16* __restrict__ iou_out, _Float16* __restrict__ f_out)
{
  int lane = threadIdx.x;
  int m = lane & 15, quad = lane >> 4;
  int cg = blockIdx.x;                 // col-group fast
  int Mtot = P << 5;
  int rowbase = blockIdx.y*64;         // row tile slow
  if (rowbase >= Mtot) return;
  int p0 = P - 1, c0 = 2*P - 1;

  int which, colbase;
  if (cg < 24)      { which = 0; colbase = cg*64; }
  else if (cg < 32) { which = 1; colbase = (cg-24)*64; }
  else              { which = 2; colbase = (cg-32)*64; }

  f32x4 acc[4][4] = {};

  int arow[4];
  #pragma unroll
  for (int i = 0; i < 4; i++){
    int r = rowbase + i*16 + m;
    arow[i] = (r < Mtot) ? r : (Mtot-1);
  }

  int nphase = leaf ? 1 : 2;
  for (int phase = 0; phase < nphase; ++phase){
    const _Float16* W;
    if (which == 0) W = (phase == 0 && !leaf) ? Wiou : Wfeiou;
    else            W = (phase == 0) ? Wf : Wfef;
    const _Float16* ap[4];
    const _Float16* wp[4];
    bool dual = (!leaf && which == 0 && phase == 0);
    #pragma unroll
    for (int i = 0; i < 4; i++){
      int r = arow[i];
      int b = r >> lp, p = r & (P-1);
      int node; const _Float16* base;
      if (leaf)            { node = 255 + p; base = feat2; }
      else if (phase == 0) { node = c0 + 2*p + ((which == 2) ? 1 : 0); base = hbuf; }
      else                 { node = p0 + p; base = feat2; }
      ap[i] = base + ((long)b*NN + node)*FEAT + quad*8;
      wp[i] = W + (long)(colbase + i*16 + m)*FEAT + quad*8;
    }

    // depth-2 software pipeline, fully unrolled; dual-add deferred to MFMA time
    half8 Ab[3][4], A2b[3][4], Bb[3][4];
    #pragma unroll
    for (int s = 0; s < 2; s++){
      long kk = (long)s*32;
      #pragma unroll
      for (int i = 0; i < 4; i++){
        Ab[s][i] = *(const half8*)(ap[i] + kk);
        if (dual) A2b[s][i] = *(const half8*)(ap[i] + FEAT + kk);
        Bb[s][i] = *(const half8*)(wp[i] + kk);
      }
    }
    #pragma unroll
    for (int ks = 0; ks < 16; ++ks){
      int cur = ks % 3;
      if (ks + 2 < 16){
        int nxt = (ks + 2) % 3;
        long kk = (long)(ks + 2)*32;
        #pragma unroll
        for (int i = 0; i < 4; i++){
          Ab[nxt][i] = *(const half8*)(ap[i] + kk);
          if (dual) A2b[nxt][i] = *(const half8*)(ap[i] + FEAT + kk);
          Bb[nxt][i] = *(const half8*)(wp[i] + kk);
        }
      }
      half8 av[4];
      #pragma unroll
      for (int i = 0; i < 4; i++){
        av[i] = Ab[cur][i];
        if (dual) av[i] = av[i] + A2b[cur][i];
      }
      #pragma unroll
      for (int i = 0; i < 4; i++)
        #pragma unroll
        for (int j = 0; j < 4; j++)
          acc[i][j] = __builtin_amdgcn_mfma_f32_16x16x32_f16(av[i], Bb[cur][j], acc[i][j], 0, 0, 0);
    }
  }

  const float* bias = (which == 0) ? biou : bf;
  #pragma unroll
  for (int j = 0; j < 4; j++){
    int n = colbase + j*16 + m;
    float bs = bias[n];
    #pragma unroll
    for (int i = 0; i < 4; i++){
      #pragma unroll
      for (int reg = 0; reg < 4; reg++){
        int r = rowbase + i*16 + quad*4 + reg;
        if (r < Mtot){
          if (which == 0)
            iou_out[(long)r*1536 + n] = (_Float16)(acc[i][j][reg] + bs);
          else
            f_out[((long)2*r + (which-1))*512 + n] = (_Float16)(acc[i][j][reg] + bs);
        }
      }
    }
  }
}

// ---------------- level-0 pointwise (leaves) ----------------
__global__ void pw_leaf(const _Float16* __restrict__ iou, float* __restrict__ c,
                        _Float16* __restrict__ h){
  int r = blockIdx.x, b = blockIdx.y, t = threadIdx.x;
  const _Float16* row = iou + ((long)b*256 + r)*1536;
  long off = ((long)b*NN + 255 + r)*FEAT;
  #pragma unroll
  for (int e = 0; e < 2; e++){
    int f = t + e*256;
    float ig = (float)row[f], og = (float)row[FEAT+f], ug = (float)row[2*FEAT+f];
    float cn = sigm(ig)*fmaxf(ug, 0.f);
    float hn = sigm(og)*tanhf(cn);
    c[off+f] = cn;
    h[off+f] = (_Float16)hn;
  }
}

// ---------------- level-n pointwise ----------------
__global__ void pw_level(const _Float16* __restrict__ iou, const _Float16* __restrict__ fbuf,
                         float* __restrict__ c, _Float16* __restrict__ h,
                         int P, int p0, int c0){
  int r = blockIdx.x, b = blockIdx.y, t = threadIdx.x;
  const _Float16* row = iou + ((long)b*P + r)*1536;
  const _Float16* fl = fbuf + ((long)b*2*P + 2*r)*FEAT;
  const _Float16* fr = fl + FEAT;
  long cl = ((long)b*NN + c0 + 2*r)*FEAT;
  long cr = cl + FEAT;
  long po = ((long)b*NN + p0 + r)*FEAT;
  #pragma unroll
  for (int e = 0; e < 2; e++){
    int f = t + e*256;
    float csum = sigm((float)fl[f])*c[cl+f] + sigm((float)fr[f])*c[cr+f];
    float cn = sigm((float)row[f])*fmaxf((float)row[2*FEAT+f], 0.f) + csum;
    float hn = sigm((float)row[FEAT+f])*tanhf(cn);
    c[po+f] = cn;
    h[po+f] = (_Float16)hn;
  }
}

// ---------------- logits[b,i] = dot(h[b,i,:], e_forw[b,:]) ----------------
__global__ void logits_kernel(const _Float16* __restrict__ h,
                              const float* __restrict__ e_forw,
                              float* __restrict__ logits){
  int b = blockIdx.y;
  int wave = threadIdx.x >> 6, lane = threadIdx.x & 63;
  int i = blockIdx.x*4 + wave;
  if (i >= NN) return;
  half8 hv = *(const half8*)(h + ((long)b*NN+i)*FEAT + lane*8);
  const float* ef = e_forw + b*FEAT + lane*8;
  float s = 0.f;
  #pragma unroll
  for (int q = 0; q < 8; q++) s += (float)hv[q]*ef[q];
  #pragma unroll
  for (int off = 32; off > 0; off >>= 1) s += __shfl_down(s, off, 64);
  if (lane == 0) logits[b*NN+i] = s;
}

// ---------------- softmax over nodes + weighted sum -> fp32 out ----------------
__global__ void out_kernel(const _Float16* __restrict__ h,
                           const float* __restrict__ logits,
                           float* __restrict__ out){
  __shared__ float sprob[NN+1];
  __shared__ float red[128];
  int b = blockIdx.x, yc = blockIdx.y, t = threadIdx.x;
  float mx = -1e30f;
  for (int i = t; i < NN; i += 128) mx = fmaxf(mx, logits[b*NN+i]);
  red[t] = mx; __syncthreads();
  for (int s = 64; s > 0; s >>= 1){ if (t < s) red[t] = fmaxf(red[t], red[t+s]); __syncthreads(); }
  mx = red[0]; __syncthreads();
  float sum = 0.f;
  for (int i = t; i < NN; i += 128){ float p = expf(logits[b*NN+i]-mx); sprob[i] = p; sum += p; }
  red[t] = sum; __syncthreads();
  for (int s = 64; s > 0; s >>= 1){ if (t < s) red[t] += red[t+s]; __syncthreads(); }
  float inv = 1.f/red[0];
  __syncthreads();
  int f = yc*128 + t;
  float acc = 0.f;
  for (int i = 0; i < NN; i++) acc += sprob[i]*(float)h[((long)b*NN+i)*FEAT+f];
  out[b*FEAT+f] = acc*inv;   // OUTPUT IS FP32
}

extern "C" void kernel_launch(void* const* d_in, const int* in_sizes, int n_in,
                              void* d_out, int out_size, void* d_ws, size_t ws_size,
                              hipStream_t stream){
  (void)in_sizes; (void)n_in; (void)out_size; (void)ws_size;
  const void* feat_raw   = d_in[0];
  const int*  finlist    = (const int*)d_in[4];
  const void* eh_raw     = d_in[5];
  const void* Wln_raw    = d_in[6];
  const void* Wlf_raw    = d_in[7];
  const void* Wiou_raw   = d_in[8];
  const void* Wfeiou_raw = d_in[9];
  const void* bfeiou_raw = d_in[10];
  const void* Wf_raw     = d_in[11];
  const void* Wfef_raw   = d_in[12];
  const void* bfef_raw   = d_in[13];

  char* ws = (char*)d_ws;
  size_t off = 0;
  auto alloc = [&](size_t bytes)->char*{
    char* p = ws + off; off += (bytes + 255) & ~(size_t)255; return p;
  };
  int*      flag     = (int*)alloc(256);
  _Float16* feat_h   = (_Float16*)alloc((size_t)NFEAT*2);
  _Float16* Wiou_h   = (_Float16*)alloc((size_t)1536*512*2);
  _Float16* Wfeiou_h = (_Float16*)alloc((size_t)1536*512*2);
  _Float16* Wf_h     = (_Float16*)alloc((size_t)512*512*2);
  _Float16* Wfef_h   = (_Float16*)alloc((size_t)512*512*2);
  _Float16* eh_h     = (_Float16*)alloc((size_t)32*1024*2);
  _Float16* Wln_h    = (_Float16*)alloc((size_t)512*1024*2);
  _Float16* Wlf_h    = (_Float16*)alloc((size_t)512*1024*2);
  float*    bfeiou_f = (float*)alloc((size_t)1536*4);
  float*    bfef_f   = (float*)alloc((size_t)512*4);
  float*    e_node   = (float*)alloc((size_t)32*512*4);
  float*    e_forw   = (float*)alloc((size_t)32*512*4);
  _Float16* feat2    = (_Float16*)alloc((size_t)NFEAT*2);
  _Float16* h_half   = (_Float16*)alloc((size_t)NFEAT*2);
  float*    c_buf    = (float*)alloc((size_t)NFEAT*4);
  _Float16* iou_buf  = (_Float16*)alloc((size_t)32*256*1536*2);
  _Float16* f_buf    = (_Float16*)alloc((size_t)32*256*512*2);
  float*    logits   = (float*)alloc((size_t)32*NN*4);

  detect_kernel<<<dim3(1), 256, 0, stream>>>((const unsigned short*)feat_raw, flag);

  cvt_all<<<dim3(5641), 256, 0, stream>>>(
      feat_raw, Wiou_raw, Wfeiou_raw, Wf_raw, Wfef_raw, eh_raw, Wln_raw, Wlf_raw,
      bfeiou_raw, bfef_raw,
      feat_h, Wiou_h, Wfeiou_h, Wf_h, Wfef_h, eh_h, Wln_h, Wlf_h,
      bfeiou_f, bfef_f, flag);

  e_mfma<<<dim3(64), 64, 0, stream>>>(eh_h, Wln_h, Wlf_h, e_node, e_forw);
  feat2_kernel<<<dim3(NN,32), 256, 0, stream>>>(feat_h, finlist, e_node, feat2);

  // level 0: leaves: M = 8192 rows; grid (colgroups=24 fast, rowtiles=128)
  gemm_level<<<dim3(24, 128), 64, 0, stream>>>(1, 256, 8,
      feat2, h_half, Wiou_h, Wfeiou_h, Wf_h, Wfef_h,
      bfeiou_f, bfef_f, iou_buf, f_buf);
  pw_leaf<<<dim3(256,32), 256, 0, stream>>>(iou_buf, c_buf, h_half);

  for (int n = 1; n <= 8; n++){
    int P = 1 << (8-n);
    int lp = 8 - n;
    int p0 = P - 1, c0 = 2*P - 1;
    int gy = (32*P + 63)/64;
    gemm_level<<<dim3(40, gy), 64, 0, stream>>>(0, P, lp,
        feat2, h_half, Wiou_h, Wfeiou_h, Wf_h, Wfef_h, bfeiou_f, bfef_f, iou_buf, f_buf);
    pw_level<<<dim3(P,32), 256, 0, stream>>>(iou_buf, f_buf, c_buf, h_half, P, p0, c0);
  }

  logits_kernel<<<dim3(128,32), 256, 0, stream>>>(h_half, e_forw, logits);
  out_kernel<<<dim3(32,4), 128, 0, stream>>>(h_half, logits, (float*)d_out);
}